// Round 4
// baseline (337.087 us; speedup 1.0000x reference)
//
#include <hip/hip_runtime.h>

typedef __attribute__((ext_vector_type(8))) short s8v;   // 8 bf16
typedef __attribute__((ext_vector_type(4))) short s4v;   // 4 bf16
typedef __attribute__((ext_vector_type(4))) float f4v;   // MFMA C/D

#define S_ 4096
#define E_ 1024
#define D_ 128

__device__ __forceinline__ unsigned short f2bf(float f) {
  unsigned int u = __float_as_uint(f);
  return (unsigned short)((u + 0x7FFFu + ((u >> 16) & 1u)) >> 16);
}

// ---- W cvt+transpose: W[p][k][n] f32 -> Wt[p*128+n][k] bf16 ----------------
__global__ __launch_bounds__(256) void wcvt_kernel(
    const float* __restrict__ Wq, const float* __restrict__ Wk,
    const float* __restrict__ Wv, unsigned short* __restrict__ Wt) {
  __shared__ unsigned short T[64][72];
  const int p = blockIdx.y;
  const float* W = (p == 0) ? Wq : (p == 1) ? Wk : Wv;
  const int k0 = (blockIdx.x >> 1) * 64;
  const int n0 = (blockIdx.x & 1) * 64;
  const int t = threadIdx.x, rr = t >> 4, c4 = (t & 15) * 4;
#pragma unroll
  for (int i = 0; i < 4; ++i) {
    int kr = i * 16 + rr;
    float4 w = *reinterpret_cast<const float4*>(W + (size_t)(k0 + kr) * D_ + n0 + c4);
    T[c4 + 0][kr] = f2bf(w.x); T[c4 + 1][kr] = f2bf(w.y);
    T[c4 + 2][kr] = f2bf(w.z); T[c4 + 3][kr] = f2bf(w.w);
  }
  __syncthreads();
#pragma unroll
  for (int i = 0; i < 4; ++i) {
    int n = i * 16 + rr;
    s4v v;
    v[0] = (short)T[n][c4]; v[1] = (short)T[n][c4 + 1];
    v[2] = (short)T[n][c4 + 2]; v[3] = (short)T[n][c4 + 3];
    *reinterpret_cast<s4v*>(Wt + (size_t)(p * D_ + n0 + n) * E_ + k0 + c4) = v;
  }
}

// ---- fused QKV projection, occupancy-first ---------------------------------
// grid 1024: block = 16 rows; 4 waves split the 384 out cols (96 each).
// All waves share the same x rows (L1); B-frags stream from L2 (Wt resident).
// 16 waves/CU for latency hiding; V written directly transposed.
__global__ __launch_bounds__(256) void proj_kernel(
    const float* __restrict__ x, const unsigned short* __restrict__ Wt,
    unsigned short* __restrict__ Qb, unsigned short* __restrict__ Kb,
    unsigned short* __restrict__ VT) {
  const int t = threadIdx.x;
  const int wv = t >> 6, lane = t & 63, quad = lane >> 4, l16 = lane & 15;
  const int m0 = blockIdx.x * 16;
  const int nb = wv * 6;  // 6 n-tiles of 16 cols per wave

  f4v acc[6];
  const f4v fz = {0.f, 0.f, 0.f, 0.f};
#pragma unroll
  for (int i = 0; i < 6; ++i) acc[i] = fz;

  const float* xp = x + (size_t)(m0 + l16) * E_ + quad * 8;
  const unsigned short* wp = Wt + (size_t)(nb * 16 + l16) * E_ + quad * 8;

  float4 a0 = *reinterpret_cast<const float4*>(xp);
  float4 a1 = *reinterpret_cast<const float4*>(xp + 4);
  for (int kk = 0; kk < E_; kk += 32) {
    float4 n0 = a0, n1 = a1;
    if (kk + 32 < E_) {  // register double-buffer for x
      n0 = *reinterpret_cast<const float4*>(xp + kk + 32);
      n1 = *reinterpret_cast<const float4*>(xp + kk + 36);
    }
    s8v af;
    af[0] = (short)f2bf(a0.x); af[1] = (short)f2bf(a0.y);
    af[2] = (short)f2bf(a0.z); af[3] = (short)f2bf(a0.w);
    af[4] = (short)f2bf(a1.x); af[5] = (short)f2bf(a1.y);
    af[6] = (short)f2bf(a1.z); af[7] = (short)f2bf(a1.w);
#pragma unroll
    for (int i = 0; i < 6; ++i) {
      s8v bf = *reinterpret_cast<const s8v*>(wp + (size_t)i * 16 * E_ + kk);
      acc[i] = __builtin_amdgcn_mfma_f32_16x16x32_bf16(af, bf, acc[i], 0, 0, 0);
    }
    a0 = n0; a1 = n1;
  }

  const int b = m0 >> 12, sbase = (m0 & (S_ - 1)) + quad * 4;
#pragma unroll
  for (int i = 0; i < 6; ++i) {
    int N = (nb + i) * 16 + l16;
    if (N < 256) {  // Q or K: row-major bf16
      unsigned short* dst = (N < 128) ? Qb : Kb;
      int col = N & 127;
#pragma unroll
      for (int r = 0; r < 4; ++r)
        dst[(size_t)(m0 + quad * 4 + r) * D_ + col] = f2bf(acc[i][r]);
    } else {  // V: transposed write VT[b][d][s]
      int d = N - 256;
      s4v v;
      v[0] = (short)f2bf(acc[i][0]); v[1] = (short)f2bf(acc[i][1]);
      v[2] = (short)f2bf(acc[i][2]); v[3] = (short)f2bf(acc[i][3]);
      *reinterpret_cast<s4v*>(VT + ((size_t)b * D_ + d) * S_ + sbase) = v;
    }
  }
}

// ---- flash attention: causal, no-max softmax, barrier-free main loop -------
// grid 1024 (4 blocks/CU): block = 16 q-rows; 4 waves key-split (32-key
// blocks, round-robin). id%8 = XCD -> batch pinning; heavy q-tiles first.
// Permuted key rows make P exit QK^T directly in K=32 A-fragment layout.
// Epilogue: 2-round LDS merge (16.3 KB only).
__global__ __launch_bounds__(256) void flash_kernel(
    const unsigned short* __restrict__ Qb, const unsigned short* __restrict__ Kb,
    const unsigned short* __restrict__ VT, float* __restrict__ out) {
  __shared__ float Ow[2][16][128];
  __shared__ float lw[4][16];
  const int id = blockIdx.x;
  const int r8 = id & 7, g = id >> 3;
  const int b = r8 >> 1;
  const int qt = 255 - (g * 2 + (r8 & 1));  // heavy-first
  const int q0 = qt * 16;
  const int t = threadIdx.x;
  const int wv = t >> 6, lane = t & 63, quad = lane >> 4, l16 = lane & 15;
  const float SCL2 = 0.03125f * 1.44269504088896340736f;  // (1/32)*log2(e)

  const unsigned short* Kbb = Kb + (size_t)b * S_ * D_;
  const unsigned short* Vbb = VT + (size_t)b * D_ * S_;

  s8v Qf[4];  // B-operand: n=l16 -> q row, k=quad*8+j -> d
#pragma unroll
  for (int ks = 0; ks < 4; ++ks)
    Qf[ks] = *reinterpret_cast<const s8v*>(
        Qb + ((size_t)b * S_ + q0 + l16) * D_ + ks * 32 + quad * 8);

  f4v O[8];
  const f4v fz = {0.f, 0.f, 0.f, 0.f};
#pragma unroll
  for (int nt = 0; nt < 8; ++nt) O[nt] = fz;
  float lt = 0.f;

  const int nkb = (q0 + 47) >> 5;
  const int keyrow = ((l16 >> 2) << 3) + (l16 & 3);  // permuted A-row -> key

  for (int kb = wv; kb < nkb; kb += 4) {
    const int k0 = kb * 32;
    s8v vfr[8];
#pragma unroll
    for (int nt = 0; nt < 8; ++nt)
      vfr[nt] = *reinterpret_cast<const s8v*>(
          Vbb + (size_t)(nt * 16 + l16) * S_ + k0 + quad * 8);
    s8v kf[2][4];
#pragma unroll
    for (int s2 = 0; s2 < 2; ++s2)
#pragma unroll
      for (int ks = 0; ks < 4; ++ks)
        kf[s2][ks] = *reinterpret_cast<const s8v*>(
            Kbb + (size_t)(k0 + keyrow + s2 * 4) * D_ + ks * 32 + quad * 8);
    f4v St[2];
    St[0] = fz; St[1] = fz;
#pragma unroll
    for (int ks = 0; ks < 4; ++ks)
#pragma unroll
      for (int s2 = 0; s2 < 2; ++s2)
        St[s2] = __builtin_amdgcn_mfma_f32_16x16x32_bf16(
            kf[s2][ks], Qf[ks], St[s2], 0, 0, 0);

    const bool full = (k0 + 31 <= q0);  // wave-uniform
    s8v pf;
#pragma unroll
    for (int s2 = 0; s2 < 2; ++s2)
#pragma unroll
      for (int r = 0; r < 4; ++r) {
        float e = exp2f(St[s2][r] * SCL2);
        if (!full) {
          int key = k0 + quad * 8 + s2 * 4 + r;
          if (key > q0 + l16) e = 0.f;
        }
        lt += e;
        pf[s2 * 4 + r] = (short)f2bf(e);
      }
#pragma unroll
    for (int nt = 0; nt < 8; ++nt)
      O[nt] = __builtin_amdgcn_mfma_f32_16x16x32_bf16(pf, vfr[nt], O[nt], 0, 0, 0);
  }

  // ---- epilogue: combine 4 key-split waves (pure sums) ----
  lt += __shfl_xor(lt, 16);
  lt += __shfl_xor(lt, 32);
  if (lane < 16) lw[wv][l16] = lt;

  if (wv >= 2) {
#pragma unroll
    for (int nt = 0; nt < 8; ++nt)
#pragma unroll
      for (int r = 0; r < 4; ++r)
        Ow[wv - 2][quad * 4 + r][nt * 16 + l16] = O[nt][r];
  }
  __syncthreads();
  if (wv < 2) {
#pragma unroll
    for (int nt = 0; nt < 8; ++nt)
#pragma unroll
      for (int r = 0; r < 4; ++r)
        O[nt][r] += Ow[wv][quad * 4 + r][nt * 16 + l16];
  }
  __syncthreads();
  if (wv == 1) {
#pragma unroll
    for (int nt = 0; nt < 8; ++nt)
#pragma unroll
      for (int r = 0; r < 4; ++r)
        Ow[0][quad * 4 + r][nt * 16 + l16] = O[nt][r];
  }
  __syncthreads();
  if (wv == 0) {
    float L[4];
#pragma unroll
    for (int r = 0; r < 4; ++r) {
      int row = quad * 4 + r;
      L[r] = lw[0][row] + lw[1][row] + lw[2][row] + lw[3][row];
    }
#pragma unroll
    for (int nt = 0; nt < 8; ++nt)
#pragma unroll
      for (int r = 0; r < 4; ++r) {
        float v = O[nt][r] + Ow[0][quad * 4 + r][nt * 16 + l16];
        out[((size_t)b * S_ + q0 + quad * 4 + r) * D_ + nt * 16 + l16] = v / L[r];
      }
  }
}

extern "C" void kernel_launch(void* const* d_in, const int* in_sizes, int n_in,
                              void* d_out, int out_size, void* d_ws, size_t ws_size,
                              hipStream_t stream) {
  const float* x = (const float*)d_in[0];
  const float* Wq = (const float*)d_in[1];
  const float* Wk = (const float*)d_in[2];
  const float* Wv = (const float*)d_in[3];
  float* out = (float*)d_out;

  unsigned short* Qb = (unsigned short*)d_ws;        // [16384][128]
  unsigned short* Kb = Qb + (size_t)16384 * 128;     // [16384][128]
  unsigned short* VT = Kb + (size_t)16384 * 128;     // [4][128][4096]
  unsigned short* Wt = VT + (size_t)16384 * 128;     // [384][1024]

  wcvt_kernel<<<dim3(32, 3), 256, 0, stream>>>(Wq, Wk, Wv, Wt);
  proj_kernel<<<1024, 256, 0, stream>>>(x, Wt, Qb, Kb, VT);
  flash_kernel<<<1024, 256, 0, stream>>>(Qb, Kb, VT, out);
}

// Round 6
// 231.887 us; speedup vs baseline: 1.4537x; 1.4537x over previous
//
#include <hip/hip_runtime.h>

typedef __attribute__((ext_vector_type(8))) short s8v;   // 8 bf16
typedef __attribute__((ext_vector_type(4))) short s4v;   // 4 bf16
typedef __attribute__((ext_vector_type(4))) float f4v;   // MFMA C/D

#define S_ 4096
#define E_ 1024
#define D_ 128

__device__ __forceinline__ unsigned short f2bf(float f) {
  unsigned int u = __float_as_uint(f);
  return (unsigned short)((u + 0x7FFFu + ((u >> 16) & 1u)) >> 16);
}

// ---- W cvt+transpose: W[p][k][n] f32 -> Wt[p*128+n][k] bf16 ----------------
__global__ __launch_bounds__(256) void wcvt_kernel(
    const float* __restrict__ Wq, const float* __restrict__ Wk,
    const float* __restrict__ Wv, unsigned short* __restrict__ Wt) {
  __shared__ unsigned short T[64][72];
  const int p = blockIdx.y;
  const float* W = (p == 0) ? Wq : (p == 1) ? Wk : Wv;
  const int k0 = (blockIdx.x >> 1) * 64;
  const int n0 = (blockIdx.x & 1) * 64;
  const int t = threadIdx.x, rr = t >> 4, c4 = (t & 15) * 4;
#pragma unroll
  for (int i = 0; i < 4; ++i) {
    int kr = i * 16 + rr;
    float4 w = *reinterpret_cast<const float4*>(W + (size_t)(k0 + kr) * D_ + n0 + c4);
    T[c4 + 0][kr] = f2bf(w.x); T[c4 + 1][kr] = f2bf(w.y);
    T[c4 + 2][kr] = f2bf(w.z); T[c4 + 3][kr] = f2bf(w.w);
  }
  __syncthreads();
#pragma unroll
  for (int i = 0; i < 4; ++i) {
    int n = i * 16 + rr;
    s4v v;
    v[0] = (short)T[n][c4]; v[1] = (short)T[n][c4 + 1];
    v[2] = (short)T[n][c4 + 2]; v[3] = (short)T[n][c4 + 3];
    *reinterpret_cast<s4v*>(Wt + (size_t)(p * D_ + n0 + n) * E_ + k0 + c4) = v;
  }
}

// ---- fused QKV projection: LDS-tiled 128x128xBK64 GEMM ---------------------
// grid (128,3). A = x (f32, converted during staging), B = Wt (bf16).
// Waves 2x2, wave-tile 64x64 (acc 4x4). Next-tile global loads issued
// during compute (register double-buffer). ng=2 writes V transposed.
__global__ __launch_bounds__(256) void proj_kernel(
    const float* __restrict__ x, const unsigned short* __restrict__ Wt,
    unsigned short* __restrict__ Qb, unsigned short* __restrict__ Kb,
    unsigned short* __restrict__ VT) {
  __shared__ __align__(16) unsigned short As[128 * 72];
  __shared__ __align__(16) unsigned short Bs[128 * 72];
  const int m0 = blockIdx.x * 128, ng = blockIdx.y;
  const int t = threadIdx.x;
  const int wv = t >> 6, lane = t & 63, quad = lane >> 4, l16 = lane & 15;
  const int wr = wv >> 1, wc = wv & 1;

  f4v acc[4][4];
  const f4v fz = {0.f, 0.f, 0.f, 0.f};
#pragma unroll
  for (int i = 0; i < 4; ++i)
#pragma unroll
    for (int j = 0; j < 4; ++j) acc[i][j] = fz;

  const int srow = t >> 1, sh = t & 1;  // staging: row 0..127, 32-elem half
  const float* xg = x + (size_t)(m0 + srow) * E_ + sh * 32;
  const unsigned short* wg = Wt + (size_t)(ng * 128 + srow) * E_ + sh * 32;

  float4 a[8];
  s8v bw[4];
#pragma unroll
  for (int i = 0; i < 8; ++i) a[i] = *reinterpret_cast<const float4*>(xg + i * 4);
#pragma unroll
  for (int i = 0; i < 4; ++i) bw[i] = *reinterpret_cast<const s8v*>(wg + i * 8);

  for (int kk = 0; kk < E_; kk += 64) {
    __syncthreads();  // previous compute done -> LDS writable
#pragma unroll
    for (int i = 0; i < 4; ++i) {
      s8v av;
      av[0] = (short)f2bf(a[2 * i].x);     av[1] = (short)f2bf(a[2 * i].y);
      av[2] = (short)f2bf(a[2 * i].z);     av[3] = (short)f2bf(a[2 * i].w);
      av[4] = (short)f2bf(a[2 * i + 1].x); av[5] = (short)f2bf(a[2 * i + 1].y);
      av[6] = (short)f2bf(a[2 * i + 1].z); av[7] = (short)f2bf(a[2 * i + 1].w);
      *reinterpret_cast<s8v*>(As + srow * 72 + sh * 32 + i * 8) = av;
      *reinterpret_cast<s8v*>(Bs + srow * 72 + sh * 32 + i * 8) = bw[i];
    }
    if (kk + 64 < E_) {  // prefetch next tiles during compute
#pragma unroll
      for (int i = 0; i < 8; ++i)
        a[i] = *reinterpret_cast<const float4*>(xg + kk + 64 + i * 4);
#pragma unroll
      for (int i = 0; i < 4; ++i)
        bw[i] = *reinterpret_cast<const s8v*>(wg + kk + 64 + i * 8);
    }
    __syncthreads();  // LDS ready
#pragma unroll
    for (int ks = 0; ks < 2; ++ks) {
      s8v af[4], bf[4];
#pragma unroll
      for (int rt = 0; rt < 4; ++rt)
        af[rt] = *reinterpret_cast<const s8v*>(
            As + (wr * 64 + rt * 16 + l16) * 72 + ks * 32 + quad * 8);
#pragma unroll
      for (int ct = 0; ct < 4; ++ct)
        bf[ct] = *reinterpret_cast<const s8v*>(
            Bs + (wc * 64 + ct * 16 + l16) * 72 + ks * 32 + quad * 8);
#pragma unroll
      for (int rt = 0; rt < 4; ++rt)
#pragma unroll
        for (int ct = 0; ct < 4; ++ct)
          acc[rt][ct] = __builtin_amdgcn_mfma_f32_16x16x32_bf16(
              af[rt], bf[ct], acc[rt][ct], 0, 0, 0);
    }
  }

  if (ng < 2) {  // Q/K row-major bf16
    unsigned short* dst = ng ? Kb : Qb;
#pragma unroll
    for (int rt = 0; rt < 4; ++rt)
#pragma unroll
      for (int ct = 0; ct < 4; ++ct)
#pragma unroll
        for (int r = 0; r < 4; ++r)
          dst[(size_t)(m0 + wr * 64 + rt * 16 + quad * 4 + r) * D_ +
              wc * 64 + ct * 16 + l16] = f2bf(acc[rt][ct][r]);
  } else {  // V transposed: VT[b][d][s]
    const int b = m0 >> 12, s0 = (m0 & (S_ - 1)) + wr * 64;
#pragma unroll
    for (int rt = 0; rt < 4; ++rt)
#pragma unroll
      for (int ct = 0; ct < 4; ++ct) {
        s4v v;
        v[0] = (short)f2bf(acc[rt][ct][0]); v[1] = (short)f2bf(acc[rt][ct][1]);
        v[2] = (short)f2bf(acc[rt][ct][2]); v[3] = (short)f2bf(acc[rt][ct][3]);
        *reinterpret_cast<s4v*>(
            VT + ((size_t)b * D_ + wc * 64 + ct * 16 + l16) * S_ + s0 +
            rt * 16 + quad * 4) = v;
      }
  }
}

// ---- flash attention: LDS-staged K/V shared by 4 q-split waves -------------
// grid 256 = (qt 0..31) x (b 0..3) x (half 0..1); q-tile 128 rows; key range
// [0, 128(qt+1)) split in 2 equal halves -> balanced blocks, 1/CU.
// K-tile XOR-swizzled, V-tile pad-80B rows: conflict-free MFMA-layout reads.
// Partial (O,l) to workspace; no-max softmax => merge is a pure sum.
__global__ __launch_bounds__(256) void flash_kernel(
    const unsigned short* __restrict__ Qb, const unsigned short* __restrict__ Kb,
    const unsigned short* __restrict__ VT, float* __restrict__ Opart,
    float* __restrict__ lpart) {
  __shared__ __align__(16) unsigned short KS[32 * 128];  // [key][d] swizzled
  __shared__ __align__(16) unsigned short VS[128 * 40];  // [d][32s +8 pad]
  const int id = blockIdx.x;
  const int qt = 31 - (id >> 3), b = (id >> 1) & 3, half = id & 1;
  const int Q0 = qt * 128;
  const int nkb2 = 2 * (qt + 1);
  const int kb_lo = half * nkb2, kb_hi = kb_lo + nkb2;
  const int t = threadIdx.x;
  const int wv = t >> 6, lane = t & 63, quad = lane >> 4, l16 = lane & 15;
  const int qrow0 = Q0 + wv * 32;
  const float SCL2 = 0.03125f * 1.44269504088896340736f;

  const unsigned short* Kbb = Kb + (size_t)b * S_ * D_;
  const unsigned short* Vbb = VT + (size_t)b * D_ * S_;

  s8v Qf[2][4];
#pragma unroll
  for (int t2 = 0; t2 < 2; ++t2)
#pragma unroll
    for (int ks = 0; ks < 4; ++ks)
      Qf[t2][ks] = *reinterpret_cast<const s8v*>(
          Qb + ((size_t)b * S_ + qrow0 + t2 * 16 + l16) * D_ + ks * 32 + quad * 8);

  f4v O[2][8];
  const f4v fz = {0.f, 0.f, 0.f, 0.f};
#pragma unroll
  for (int t2 = 0; t2 < 2; ++t2)
#pragma unroll
    for (int nt = 0; nt < 8; ++nt) O[t2][nt] = fz;
  float lt[2] = {0.f, 0.f};

  // staging assignments
  const int krow = t >> 4, kgb = t & 15;   // K: rows krow, krow+16; 16B granule
  const int vd = t >> 2, vgs = t & 3;      // V: d rows vd, vd+64
  const int sw0 = (krow & 3) | (((krow >> 3) & 1) << 2);
  const int sw1 = ((krow + 16) & 3) | ((((krow + 16) >> 3) & 1) << 2);

  s8v kr0, kr1, vr0, vr1;
  {
    const int k0 = kb_lo * 32;
    kr0 = *reinterpret_cast<const s8v*>(Kbb + (size_t)(k0 + krow) * D_ + kgb * 8);
    kr1 = *reinterpret_cast<const s8v*>(Kbb + (size_t)(k0 + krow + 16) * D_ + kgb * 8);
    vr0 = *reinterpret_cast<const s8v*>(Vbb + (size_t)vd * S_ + k0 + vgs * 8);
    vr1 = *reinterpret_cast<const s8v*>(Vbb + (size_t)(vd + 64) * S_ + k0 + vgs * 8);
  }

  for (int kb = kb_lo; kb < kb_hi; ++kb) {
    const int k0 = kb * 32;
    __syncthreads();  // previous compute done reading LDS
    *reinterpret_cast<s8v*>(KS + krow * 128 + (kgb ^ sw0) * 8) = kr0;
    *reinterpret_cast<s8v*>(KS + (krow + 16) * 128 + (kgb ^ sw1) * 8) = kr1;
    *reinterpret_cast<s8v*>(VS + vd * 40 + vgs * 8) = vr0;
    *reinterpret_cast<s8v*>(VS + (vd + 64) * 40 + vgs * 8) = vr1;
    if (kb + 1 < kb_hi) {  // prefetch next tile during compute
      const int k1 = k0 + 32;
      kr0 = *reinterpret_cast<const s8v*>(Kbb + (size_t)(k1 + krow) * D_ + kgb * 8);
      kr1 = *reinterpret_cast<const s8v*>(Kbb + (size_t)(k1 + krow + 16) * D_ + kgb * 8);
      vr0 = *reinterpret_cast<const s8v*>(Vbb + (size_t)vd * S_ + k1 + vgs * 8);
      vr1 = *reinterpret_cast<const s8v*>(Vbb + (size_t)(vd + 64) * S_ + k1 + vgs * 8);
    }
    __syncthreads();  // LDS ready

    if (k0 <= qrow0 + 31) {  // wave-uniform causal skip
      f4v St[2][2];
      St[0][0] = fz; St[0][1] = fz; St[1][0] = fz; St[1][1] = fz;
#pragma unroll
      for (int ks = 0; ks < 4; ++ks)
#pragma unroll
        for (int s2 = 0; s2 < 2; ++s2) {
          const int row = ((l16 >> 2) << 3) + s2 * 4 + (l16 & 3);
          const int g = (ks * 4 + quad) ^ ((row & 3) | (((row >> 3) & 1) << 2));
          s8v kf = *reinterpret_cast<const s8v*>(KS + row * 128 + g * 8);
#pragma unroll
          for (int t2 = 0; t2 < 2; ++t2)
            St[s2][t2] = __builtin_amdgcn_mfma_f32_16x16x32_bf16(
                kf, Qf[t2][ks], St[s2][t2], 0, 0, 0);
        }
      const bool full = (k0 + 31 <= qrow0);
      s8v pf[2];
#pragma unroll
      for (int t2 = 0; t2 < 2; ++t2) {
        float ladd = 0.f;
#pragma unroll
        for (int s2 = 0; s2 < 2; ++s2)
#pragma unroll
          for (int r = 0; r < 4; ++r) {
            float e = exp2f(St[s2][t2][r] * SCL2);
            if (!full) {
              int key = k0 + quad * 8 + s2 * 4 + r;
              if (key > qrow0 + t2 * 16 + l16) e = 0.f;
            }
            ladd += e;
            pf[t2][s2 * 4 + r] = (short)f2bf(e);
          }
        lt[t2] += ladd;
      }
#pragma unroll
      for (int nt = 0; nt < 8; ++nt) {
        s8v vf = *reinterpret_cast<const s8v*>(VS + (nt * 16 + l16) * 40 + quad * 8);
#pragma unroll
        for (int t2 = 0; t2 < 2; ++t2)
          O[t2][nt] = __builtin_amdgcn_mfma_f32_16x16x32_bf16(
              pf[t2], vf, O[t2][nt], 0, 0, 0);
      }
    }
  }

  // epilogue: each wave owns its 32 q-rows — no cross-wave combine needed
#pragma unroll
  for (int t2 = 0; t2 < 2; ++t2) {
    lt[t2] += __shfl_xor(lt[t2], 16);
    lt[t2] += __shfl_xor(lt[t2], 32);
  }
  const size_t pbase = ((size_t)half * 4 + b) * S_ * D_;
#pragma unroll
  for (int t2 = 0; t2 < 2; ++t2)
#pragma unroll
    for (int nt = 0; nt < 8; ++nt)
#pragma unroll
      for (int r = 0; r < 4; ++r)
        Opart[pbase + (size_t)(qrow0 + t2 * 16 + quad * 4 + r) * D_ +
              nt * 16 + l16] = O[t2][nt][r];
  if (lane < 16) {
    lpart[((size_t)half * 4 + b) * S_ + qrow0 + l16] = lt[0];
    lpart[((size_t)half * 4 + b) * S_ + qrow0 + 16 + l16] = lt[1];
  }
}

// ---- merge: out = (O0+O1)/(l0+l1) ------------------------------------------
__global__ __launch_bounds__(256) void merge_kernel(
    const float* __restrict__ Opart, const float* __restrict__ lpart,
    float* __restrict__ out) {
  const int idx = blockIdx.x * 256 + threadIdx.x;  // x4 floats
  const int base = idx * 4;
  const int row = base >> 7;  // 0..16383 (b*4096+s)
  float4 o0 = *reinterpret_cast<const float4*>(Opart + (size_t)row * D_ + (base & 127));
  float4 o1 = *reinterpret_cast<const float4*>(
      Opart + (size_t)(16384 + row) * D_ + (base & 127));
  float L = lpart[row] + lpart[16384 + row];
  float4 r;
  r.x = (o0.x + o1.x) / L; r.y = (o0.y + o1.y) / L;
  r.z = (o0.z + o1.z) / L; r.w = (o0.w + o1.w) / L;
  *reinterpret_cast<float4*>(out + base) = r;
}

extern "C" void kernel_launch(void* const* d_in, const int* in_sizes, int n_in,
                              void* d_out, int out_size, void* d_ws, size_t ws_size,
                              hipStream_t stream) {
  const float* x = (const float*)d_in[0];
  const float* Wq = (const float*)d_in[1];
  const float* Wk = (const float*)d_in[2];
  const float* Wv = (const float*)d_in[3];
  float* out = (float*)d_out;

  char* ws = (char*)d_ws;
  unsigned short* Qb = (unsigned short*)ws;                          // 4 MB
  unsigned short* Kb = (unsigned short*)(ws + (((size_t)4) << 20));  // 4 MB
  unsigned short* VT = (unsigned short*)(ws + (((size_t)8) << 20));  // 4 MB
  unsigned short* Wt = (unsigned short*)(ws + (((size_t)12) << 20)); // 0.75 MB
  float* Opart = (float*)(ws + (((size_t)13) << 20));                // 16 MB
  float* lpart = (float*)(ws + (((size_t)29) << 20));                // 128 KB

  wcvt_kernel<<<dim3(32, 3), 256, 0, stream>>>(Wq, Wk, Wv, Wt);
  proj_kernel<<<dim3(128, 3), 256, 0, stream>>>(x, Wt, Qb, Kb, VT);
  flash_kernel<<<256, 256, 0, stream>>>(Qb, Kb, VT, Opart, lpart);
  merge_kernel<<<2048, 256, 0, stream>>>(Opart, lpart, out);
}

// Round 7
// 220.540 us; speedup vs baseline: 1.5285x; 1.0514x over previous
//
#include <hip/hip_runtime.h>

typedef __attribute__((ext_vector_type(8))) short s8v;   // 8 bf16
typedef __attribute__((ext_vector_type(4))) short s4v;   // 4 bf16
typedef __attribute__((ext_vector_type(4))) float f4v;   // MFMA C/D

#define S_ 4096
#define E_ 1024
#define D_ 128

__device__ __forceinline__ unsigned short f2bf(float f) {
  unsigned int u = __float_as_uint(f);
  return (unsigned short)((u + 0x7FFFu + ((u >> 16) & 1u)) >> 16);
}

// ---- zero the accumulators (ws is re-poisoned before every launch) ---------
__global__ __launch_bounds__(256) void zero_kernel(float* __restrict__ p) {
  const int i = blockIdx.x * 256 + threadIdx.x;
  float4 z = {0.f, 0.f, 0.f, 0.f};
  reinterpret_cast<float4*>(p)[i] = z;
}

// ---- W cvt+transpose: W[p][k][n] f32 -> Wt[p*128+n][k] bf16 ----------------
__global__ __launch_bounds__(256) void wcvt_kernel(
    const float* __restrict__ Wq, const float* __restrict__ Wk,
    const float* __restrict__ Wv, unsigned short* __restrict__ Wt) {
  __shared__ unsigned short T[64][72];
  const int p = blockIdx.y;
  const float* W = (p == 0) ? Wq : (p == 1) ? Wk : Wv;
  const int k0 = (blockIdx.x >> 1) * 64;
  const int n0 = (blockIdx.x & 1) * 64;
  const int t = threadIdx.x, rr = t >> 4, c4 = (t & 15) * 4;
#pragma unroll
  for (int i = 0; i < 4; ++i) {
    int kr = i * 16 + rr;
    float4 w = *reinterpret_cast<const float4*>(W + (size_t)(k0 + kr) * D_ + n0 + c4);
    T[c4 + 0][kr] = f2bf(w.x); T[c4 + 1][kr] = f2bf(w.y);
    T[c4 + 2][kr] = f2bf(w.z); T[c4 + 3][kr] = f2bf(w.w);
  }
  __syncthreads();
#pragma unroll
  for (int i = 0; i < 4; ++i) {
    int n = i * 16 + rr;
    s4v v;
    v[0] = (short)T[n][c4]; v[1] = (short)T[n][c4 + 1];
    v[2] = (short)T[n][c4 + 2]; v[3] = (short)T[n][c4 + 3];
    *reinterpret_cast<s4v*>(Wt + (size_t)(p * D_ + n0 + n) * E_ + k0 + c4) = v;
  }
}

// ---- fused QKV projection: 64x128xBK64 LDS GEMM, XCD-classed ---------------
// grid 768 flat: class c = bid&7 (XCD), j = bid>>3; mt = c*32 + j/3, ng = j%3.
// The 3 n-groups of one M-tile share an XCD -> x fetched once from HBM.
// 3 blocks/CU, 27.6 KB LDS. ng: 0=Q, 1=K, 2=V(transposed).
__global__ __launch_bounds__(256) void proj_kernel(
    const float* __restrict__ x, const unsigned short* __restrict__ Wt,
    unsigned short* __restrict__ Qb, unsigned short* __restrict__ Kb,
    unsigned short* __restrict__ VT) {
  __shared__ __align__(16) unsigned short As[64 * 72];
  __shared__ __align__(16) unsigned short Bs[128 * 72];
  const int bid = blockIdx.x;
  const int cls = bid & 7, j = bid >> 3;
  const int m0 = (cls * 32 + j / 3) * 64, ng = j % 3;
  const int t = threadIdx.x;
  const int wv = t >> 6, lane = t & 63, quad = lane >> 4, l16 = lane & 15;
  const int wr = wv >> 1, wc = wv & 1;  // wave-tile 32x64

  f4v acc[2][4];
  const f4v fz = {0.f, 0.f, 0.f, 0.f};
#pragma unroll
  for (int i = 0; i < 2; ++i)
#pragma unroll
    for (int k = 0; k < 4; ++k) acc[i][k] = fz;

  const int arow = t >> 2, aq = t & 3;   // A: 64 rows x 4 k-quarters
  const int brow = t >> 1, bh = t & 1;   // B: 128 rows x 2 k-halves
  const float* xg = x + (size_t)(m0 + arow) * E_ + aq * 16;
  const unsigned short* wg = Wt + (size_t)(ng * 128 + brow) * E_ + bh * 32;

  float4 xa[4];
  s8v wb[4];
#pragma unroll
  for (int i = 0; i < 4; ++i) xa[i] = *reinterpret_cast<const float4*>(xg + i * 4);
#pragma unroll
  for (int i = 0; i < 4; ++i) wb[i] = *reinterpret_cast<const s8v*>(wg + i * 8);

  for (int kk = 0; kk < E_; kk += 64) {
    __syncthreads();
#pragma unroll
    for (int i = 0; i < 2; ++i) {
      s8v av;
      av[0] = (short)f2bf(xa[2 * i].x);     av[1] = (short)f2bf(xa[2 * i].y);
      av[2] = (short)f2bf(xa[2 * i].z);     av[3] = (short)f2bf(xa[2 * i].w);
      av[4] = (short)f2bf(xa[2 * i + 1].x); av[5] = (short)f2bf(xa[2 * i + 1].y);
      av[6] = (short)f2bf(xa[2 * i + 1].z); av[7] = (short)f2bf(xa[2 * i + 1].w);
      *reinterpret_cast<s8v*>(As + arow * 72 + aq * 16 + i * 8) = av;
    }
#pragma unroll
    for (int i = 0; i < 4; ++i)
      *reinterpret_cast<s8v*>(Bs + brow * 72 + bh * 32 + i * 8) = wb[i];
    if (kk + 64 < E_) {
#pragma unroll
      for (int i = 0; i < 4; ++i)
        xa[i] = *reinterpret_cast<const float4*>(xg + kk + 64 + i * 4);
#pragma unroll
      for (int i = 0; i < 4; ++i)
        wb[i] = *reinterpret_cast<const s8v*>(wg + kk + 64 + i * 8);
    }
    __syncthreads();
#pragma unroll
    for (int ks = 0; ks < 2; ++ks) {
      s8v af[2], bf[4];
#pragma unroll
      for (int rt = 0; rt < 2; ++rt)
        af[rt] = *reinterpret_cast<const s8v*>(
            As + (wr * 32 + rt * 16 + l16) * 72 + ks * 32 + quad * 8);
#pragma unroll
      for (int ct = 0; ct < 4; ++ct)
        bf[ct] = *reinterpret_cast<const s8v*>(
            Bs + (wc * 64 + ct * 16 + l16) * 72 + ks * 32 + quad * 8);
#pragma unroll
      for (int rt = 0; rt < 2; ++rt)
#pragma unroll
        for (int ct = 0; ct < 4; ++ct)
          acc[rt][ct] = __builtin_amdgcn_mfma_f32_16x16x32_bf16(
              af[rt], bf[ct], acc[rt][ct], 0, 0, 0);
    }
  }

  if (ng < 2) {
    unsigned short* dst = ng ? Kb : Qb;
#pragma unroll
    for (int rt = 0; rt < 2; ++rt)
#pragma unroll
      for (int ct = 0; ct < 4; ++ct)
#pragma unroll
        for (int r = 0; r < 4; ++r)
          dst[(size_t)(m0 + wr * 32 + rt * 16 + quad * 4 + r) * D_ +
              wc * 64 + ct * 16 + l16] = f2bf(acc[rt][ct][r]);
  } else {
    const int b = m0 >> 12;
    const int s0 = (m0 & (S_ - 1)) + wr * 32;
#pragma unroll
    for (int rt = 0; rt < 2; ++rt)
#pragma unroll
      for (int ct = 0; ct < 4; ++ct) {
        s4v v;
        v[0] = (short)f2bf(acc[rt][ct][0]); v[1] = (short)f2bf(acc[rt][ct][1]);
        v[2] = (short)f2bf(acc[rt][ct][2]); v[3] = (short)f2bf(acc[rt][ct][3]);
        *reinterpret_cast<s4v*>(
            VT + ((size_t)b * D_ + wc * 64 + ct * 16 + l16) * S_ + s0 +
            rt * 16 + quad * 4) = v;
      }
  }
}

// ---- flash: balanced (qt, 512-key chunk) blocks, 64-key LDS tiles ----------
// grid (144, 4): per batch, block = (qt, s), s over ceil((qt+1)/4) chunks of
// 512 keys -> 576 blocks of <=8 iters (2.25/CU, ~2 co-resident). 4 waves
// q-split (32 rows each) share the staged K/V tile. No-max exp2 softmax;
// partial (O,l) accumulated with device-scope float atomics (Oacc zeroed).
__global__ __launch_bounds__(256) void flash_kernel(
    const unsigned short* __restrict__ Qb, const unsigned short* __restrict__ Kb,
    const unsigned short* __restrict__ VT, float* __restrict__ Oacc,
    float* __restrict__ Lacc) {
  __shared__ __align__(16) unsigned short KS[64 * 128];  // [key][d] swizzled
  __shared__ __align__(16) unsigned short VS[128 * 72];  // [d][64s + 8 pad]
  // decode (qt, s): group g = qt>>2 has 4 qts x (g+1) chunks; C(g)=2(g+1)(g+2)
  const int id = 143 - blockIdx.x;  // heavy-ish first
  int g = 0;
#pragma unroll
  for (int gg = 0; gg < 8; ++gg)
    if (id >= 2 * (gg + 1) * (gg + 2)) g = gg + 1;
  const int off = id - 2 * g * (g + 1);
  const int qt = 4 * g + off / (g + 1);
  const int s = off % (g + 1);
  const int b = blockIdx.y;
  const int q0 = qt * 128;
  const int klo = s * 512;
  const int khi = min((s + 1) * 512, (qt + 1) * 128);

  const int t = threadIdx.x;
  const int wv = t >> 6, lane = t & 63, quad = lane >> 4, l16 = lane & 15;
  const int qrow0 = q0 + wv * 32;
  const float SCL2 = 0.03125f * 1.44269504088896340736f;  // (1/32)*log2(e)

  const unsigned short* Kbb = Kb + (size_t)b * S_ * D_;
  const unsigned short* Vbb = VT + (size_t)b * D_ * S_;

  s8v Qf[2][4];
#pragma unroll
  for (int t2 = 0; t2 < 2; ++t2)
#pragma unroll
    for (int ks = 0; ks < 4; ++ks)
      Qf[t2][ks] = *reinterpret_cast<const s8v*>(
          Qb + ((size_t)b * S_ + qrow0 + t2 * 16 + l16) * D_ + ks * 32 + quad * 8);

  f4v O[2][8];
  const f4v fz = {0.f, 0.f, 0.f, 0.f};
#pragma unroll
  for (int t2 = 0; t2 < 2; ++t2)
#pragma unroll
    for (int nt = 0; nt < 8; ++nt) O[t2][nt] = fz;
  float lt[2] = {0.f, 0.f};

  // staging: K rows krow+{0,16,32,48} granule kgb; V rows vrow, 4 granules
  const int krow = t >> 4, kgb = t & 15;
  const int swr = (krow & 3) | (((krow >> 3) & 1) << 2);
  const int vrow = t >> 1, vgb = (t & 1) * 4;
  const int swl = (l16 & 3) | (((l16 >> 2) & 1) << 2);  // read-side swizzle

  s8v kr[4], vr[4];
#pragma unroll
  for (int i = 0; i < 4; ++i) {
    kr[i] = *reinterpret_cast<const s8v*>(
        Kbb + (size_t)(klo + krow + 16 * i) * D_ + kgb * 8);
    vr[i] = *reinterpret_cast<const s8v*>(
        Vbb + (size_t)vrow * S_ + klo + (vgb + i) * 8);
  }

  for (int k0 = klo; k0 < khi; k0 += 64) {
    __syncthreads();
#pragma unroll
    for (int i = 0; i < 4; ++i) {
      *reinterpret_cast<s8v*>(KS + (krow + 16 * i) * 128 + ((kgb ^ swr) * 8)) = kr[i];
      *reinterpret_cast<s8v*>(VS + vrow * 72 + (vgb + i) * 8) = vr[i];
    }
    if (k0 + 64 < khi) {
#pragma unroll
      for (int i = 0; i < 4; ++i) {
        kr[i] = *reinterpret_cast<const s8v*>(
            Kbb + (size_t)(k0 + 64 + krow + 16 * i) * D_ + kgb * 8);
        vr[i] = *reinterpret_cast<const s8v*>(
            Vbb + (size_t)vrow * S_ + k0 + 64 + (vgb + i) * 8);
      }
    }
    __syncthreads();

    if (k0 <= qrow0 + 31) {  // wave-uniform causal skip
      f4v St[2][2][2];  // [chunk c][s2][t2]
#pragma unroll
      for (int c = 0; c < 2; ++c)
#pragma unroll
        for (int s2 = 0; s2 < 2; ++s2)
#pragma unroll
          for (int t2 = 0; t2 < 2; ++t2) St[c][s2][t2] = fz;
#pragma unroll
      for (int ks = 0; ks < 4; ++ks)
#pragma unroll
        for (int c = 0; c < 2; ++c)
#pragma unroll
          for (int s2 = 0; s2 < 2; ++s2) {
            const int row = c * 32 + ((l16 >> 2) << 3) + s2 * 4 + (l16 & 3);
            s8v kf = *reinterpret_cast<const s8v*>(
                KS + row * 128 + (((ks * 4 + quad) ^ swl) * 8));
#pragma unroll
            for (int t2 = 0; t2 < 2; ++t2)
              St[c][s2][t2] = __builtin_amdgcn_mfma_f32_16x16x32_bf16(
                  kf, Qf[t2][ks], St[c][s2][t2], 0, 0, 0);
          }
      const bool full = (k0 + 63 <= qrow0);
      s8v pf[2][2];  // [c][t2]
#pragma unroll
      for (int c = 0; c < 2; ++c)
#pragma unroll
        for (int t2 = 0; t2 < 2; ++t2) {
          float ladd = 0.f;
#pragma unroll
          for (int s2 = 0; s2 < 2; ++s2)
#pragma unroll
            for (int r = 0; r < 4; ++r) {
              float e = exp2f(St[c][s2][t2][r] * SCL2);
              if (!full) {
                int key = k0 + c * 32 + quad * 8 + s2 * 4 + r;
                if (key > qrow0 + t2 * 16 + l16) e = 0.f;
              }
              ladd += e;
              pf[c][t2][s2 * 4 + r] = (short)f2bf(e);
            }
          lt[t2] += ladd;
        }
#pragma unroll
      for (int c = 0; c < 2; ++c)
#pragma unroll
        for (int nt = 0; nt < 8; ++nt) {
          s8v vf = *reinterpret_cast<const s8v*>(
              VS + (nt * 16 + l16) * 72 + (c * 4 + quad) * 8);
#pragma unroll
          for (int t2 = 0; t2 < 2; ++t2)
            O[t2][nt] = __builtin_amdgcn_mfma_f32_16x16x32_bf16(
                pf[c][t2], vf, O[t2][nt], 0, 0, 0);
        }
    }
  }

  // epilogue: atomically accumulate partial (O, l)
#pragma unroll
  for (int t2 = 0; t2 < 2; ++t2) {
    lt[t2] += __shfl_xor(lt[t2], 16);
    lt[t2] += __shfl_xor(lt[t2], 32);
  }
  float* Ob = Oacc + (size_t)b * S_ * D_;
#pragma unroll
  for (int t2 = 0; t2 < 2; ++t2)
#pragma unroll
    for (int nt = 0; nt < 8; ++nt)
#pragma unroll
      for (int r = 0; r < 4; ++r)
        atomicAdd(&Ob[(size_t)(qrow0 + t2 * 16 + quad * 4 + r) * D_ +
                      nt * 16 + l16], O[t2][nt][r]);
  if (lane < 16) atomicAdd(&Lacc[(size_t)b * S_ + qrow0 + l16], lt[0]);
  else if (lane < 32) atomicAdd(&Lacc[(size_t)b * S_ + qrow0 + 16 + (lane & 15)], lt[1]);
}

// ---- normalize: out = Oacc / Lacc ------------------------------------------
__global__ __launch_bounds__(256) void norm_kernel(
    const float* __restrict__ Oacc, const float* __restrict__ Lacc,
    float* __restrict__ out) {
  const int idx = blockIdx.x * 256 + threadIdx.x;
  const int base = idx * 4;
  const int row = base >> 7;
  float4 o = reinterpret_cast<const float4*>(Oacc)[idx];
  float L = Lacc[row];
  float4 r;
  r.x = o.x / L; r.y = o.y / L; r.z = o.z / L; r.w = o.w / L;
  reinterpret_cast<float4*>(out)[idx] = r;
}

extern "C" void kernel_launch(void* const* d_in, const int* in_sizes, int n_in,
                              void* d_out, int out_size, void* d_ws, size_t ws_size,
                              hipStream_t stream) {
  const float* x = (const float*)d_in[0];
  const float* Wq = (const float*)d_in[1];
  const float* Wk = (const float*)d_in[2];
  const float* Wv = (const float*)d_in[3];
  float* out = (float*)d_out;

  char* ws = (char*)d_ws;
  unsigned short* Qb = (unsigned short*)ws;                           // 4 MB
  unsigned short* Kb = (unsigned short*)(ws + (((size_t)4) << 20));   // 4 MB
  unsigned short* VT = (unsigned short*)(ws + (((size_t)8) << 20));   // 4 MB
  unsigned short* Wt = (unsigned short*)(ws + (((size_t)12) << 20));  // 0.75 MB
  float* Oacc = (float*)(ws + (((size_t)13) << 20));                  // 8 MB
  float* Lacc = (float*)(ws + (((size_t)21) << 20));                  // 64 KB
  // zero covers Oacc + Lacc contiguously: (8 MB + 64 KB)/16 B = 528384 f4
  zero_kernel<<<2064, 256, 0, stream>>>(Oacc);
  wcvt_kernel<<<dim3(32, 3), 256, 0, stream>>>(Wq, Wk, Wv, Wt);
  proj_kernel<<<768, 256, 0, stream>>>(x, Wt, Qb, Kb, VT);
  flash_kernel<<<dim3(144, 4), 256, 0, stream>>>(Qb, Kb, VT, Oacc, Lacc);
  norm_kernel<<<2048, 256, 0, stream>>>(Oacc, Lacc, out);
}

// Round 8
// 220.020 us; speedup vs baseline: 1.5321x; 1.0024x over previous
//
#include <hip/hip_runtime.h>

typedef __attribute__((ext_vector_type(8))) short s8v;   // 8 bf16
typedef __attribute__((ext_vector_type(4))) short s4v;   // 4 bf16
typedef __attribute__((ext_vector_type(4))) float f4v;   // MFMA C/D

#define S_ 4096
#define E_ 1024
#define D_ 128

__device__ __forceinline__ unsigned short f2bf(float f) {
  unsigned int u = __float_as_uint(f);
  return (unsigned short)((u + 0x7FFFu + ((u >> 16) & 1u)) >> 16);
}

// ---- zero the accumulators -------------------------------------------------
__global__ __launch_bounds__(256) void zero_kernel(float* __restrict__ p) {
  const int i = blockIdx.x * 256 + threadIdx.x;
  float4 z = {0.f, 0.f, 0.f, 0.f};
  reinterpret_cast<float4*>(p)[i] = z;
}

// ---- W cvt+transpose: W[p][k][n] f32 -> Wt[p*128+n][k] bf16 ----------------
__global__ __launch_bounds__(256) void wcvt_kernel(
    const float* __restrict__ Wq, const float* __restrict__ Wk,
    const float* __restrict__ Wv, unsigned short* __restrict__ Wt) {
  __shared__ unsigned short T[64][72];
  const int p = blockIdx.y;
  const float* W = (p == 0) ? Wq : (p == 1) ? Wk : Wv;
  const int k0 = (blockIdx.x >> 1) * 64;
  const int n0 = (blockIdx.x & 1) * 64;
  const int t = threadIdx.x, rr = t >> 4, c4 = (t & 15) * 4;
#pragma unroll
  for (int i = 0; i < 4; ++i) {
    int kr = i * 16 + rr;
    float4 w = *reinterpret_cast<const float4*>(W + (size_t)(k0 + kr) * D_ + n0 + c4);
    T[c4 + 0][kr] = f2bf(w.x); T[c4 + 1][kr] = f2bf(w.y);
    T[c4 + 2][kr] = f2bf(w.z); T[c4 + 3][kr] = f2bf(w.w);
  }
  __syncthreads();
#pragma unroll
  for (int i = 0; i < 4; ++i) {
    int n = i * 16 + rr;
    s4v v;
    v[0] = (short)T[n][c4]; v[1] = (short)T[n][c4 + 1];
    v[2] = (short)T[n][c4 + 2]; v[3] = (short)T[n][c4 + 3];
    *reinterpret_cast<s4v*>(Wt + (size_t)(p * D_ + n0 + n) * E_ + k0 + c4) = v;
  }
}

// ---- fused QKV projection: 64x128xBK64 LDS GEMM, fixed pipeline ------------
// grid 768: cls = bid&7 (XCD class), mt = cls*32 + j/3, ng = j%3 — the 3
// n-groups of one M-tile share an XCD (x read once from HBM, L2-hit after).
// Pipeline: barrier / stage regs->LDS / barrier / ISSUE next loads / compute
// so global loads are in flight during compute (drained at next barrier).
__global__ __launch_bounds__(256) void proj_kernel(
    const float* __restrict__ x, const unsigned short* __restrict__ Wt,
    unsigned short* __restrict__ Qb, unsigned short* __restrict__ Kb,
    unsigned short* __restrict__ VT) {
  __shared__ __align__(16) unsigned short As[64 * 72];
  __shared__ __align__(16) unsigned short Bs[128 * 72];
  const int bid = blockIdx.x;
  const int cls = bid & 7, j = bid >> 3;
  const int m0 = (cls * 32 + j / 3) * 64, ng = j % 3;
  const int t = threadIdx.x;
  const int wv = t >> 6, lane = t & 63, quad = lane >> 4, l16 = lane & 15;
  const int wr = wv >> 1, wc = wv & 1;  // wave-tile 32x64

  f4v acc[2][4];
  const f4v fz = {0.f, 0.f, 0.f, 0.f};
#pragma unroll
  for (int i = 0; i < 2; ++i)
#pragma unroll
    for (int k = 0; k < 4; ++k) acc[i][k] = fz;

  const int arow = t >> 2, aq = t & 3;   // A: 64 rows x 4 k-quarters (16 f32)
  const int brow = t >> 1, bh = t & 1;   // B: 128 rows x 2 k-halves (32 bf16)
  const float* xg = x + (size_t)(m0 + arow) * E_ + aq * 16;
  const unsigned short* wg = Wt + (size_t)(ng * 128 + brow) * E_ + bh * 32;

  float4 xa[4];
  s8v wb[4];
#pragma unroll
  for (int i = 0; i < 4; ++i) xa[i] = *reinterpret_cast<const float4*>(xg + i * 4);
#pragma unroll
  for (int i = 0; i < 4; ++i) wb[i] = *reinterpret_cast<const s8v*>(wg + i * 8);

  for (int kk = 0; kk < E_; kk += 64) {
    __syncthreads();
#pragma unroll
    for (int i = 0; i < 2; ++i) {
      s8v av;
      av[0] = (short)f2bf(xa[2 * i].x);     av[1] = (short)f2bf(xa[2 * i].y);
      av[2] = (short)f2bf(xa[2 * i].z);     av[3] = (short)f2bf(xa[2 * i].w);
      av[4] = (short)f2bf(xa[2 * i + 1].x); av[5] = (short)f2bf(xa[2 * i + 1].y);
      av[6] = (short)f2bf(xa[2 * i + 1].z); av[7] = (short)f2bf(xa[2 * i + 1].w);
      *reinterpret_cast<s8v*>(As + arow * 72 + aq * 16 + i * 8) = av;
    }
#pragma unroll
    for (int i = 0; i < 4; ++i)
      *reinterpret_cast<s8v*>(Bs + brow * 72 + bh * 32 + i * 8) = wb[i];
    __syncthreads();
    if (kk + 64 < E_) {  // issue next-tile loads NOW; they fly during compute
#pragma unroll
      for (int i = 0; i < 4; ++i)
        xa[i] = *reinterpret_cast<const float4*>(xg + kk + 64 + i * 4);
#pragma unroll
      for (int i = 0; i < 4; ++i)
        wb[i] = *reinterpret_cast<const s8v*>(wg + kk + 64 + i * 8);
    }
#pragma unroll
    for (int ks = 0; ks < 2; ++ks) {
      s8v af[2], bf[4];
#pragma unroll
      for (int rt = 0; rt < 2; ++rt)
        af[rt] = *reinterpret_cast<const s8v*>(
            As + (wr * 32 + rt * 16 + l16) * 72 + ks * 32 + quad * 8);
#pragma unroll
      for (int ct = 0; ct < 4; ++ct)
        bf[ct] = *reinterpret_cast<const s8v*>(
            Bs + (wc * 64 + ct * 16 + l16) * 72 + ks * 32 + quad * 8);
#pragma unroll
      for (int rt = 0; rt < 2; ++rt)
#pragma unroll
        for (int ct = 0; ct < 4; ++ct)
          acc[rt][ct] = __builtin_amdgcn_mfma_f32_16x16x32_bf16(
              af[rt], bf[ct], acc[rt][ct], 0, 0, 0);
    }
  }

  if (ng < 2) {
    unsigned short* dst = ng ? Kb : Qb;
#pragma unroll
    for (int rt = 0; rt < 2; ++rt)
#pragma unroll
      for (int ct = 0; ct < 4; ++ct)
#pragma unroll
        for (int r = 0; r < 4; ++r)
          dst[(size_t)(m0 + wr * 32 + rt * 16 + quad * 4 + r) * D_ +
              wc * 64 + ct * 16 + l16] = f2bf(acc[rt][ct][r]);
  } else {
    const int b = m0 >> 12;
    const int s0 = (m0 & (S_ - 1)) + wr * 32;
#pragma unroll
    for (int rt = 0; rt < 2; ++rt)
#pragma unroll
      for (int ct = 0; ct < 4; ++ct) {
        s4v v;
        v[0] = (short)f2bf(acc[rt][ct][0]); v[1] = (short)f2bf(acc[rt][ct][1]);
        v[2] = (short)f2bf(acc[rt][ct][2]); v[3] = (short)f2bf(acc[rt][ct][3]);
        *reinterpret_cast<s4v*>(
            VT + ((size_t)b * D_ + wc * 64 + ct * 16 + l16) * S_ + s0 +
            rt * 16 + quad * 4) = v;
      }
  }
}

// ---- flash: balanced blocks, fixed pipeline, XOR-16 KS swizzle -------------
// grid 576: xcd = id&7 -> (batch, half-class); sub = heavy-first (qt, s)
// triangular decode; block = 128 q-rows x one 512-key chunk (<=8 64-key
// iters). KS element (key r, d-granule g) stored at position g ^ sigma(r),
// sigma(r) = (r&3)|(((r>>3)&3)<<2)  =>  QK read position (ks*4+quad)^l16:
// all 16 granules per quad = minimum bank rounds both sides.
__global__ __launch_bounds__(256) void flash_kernel(
    const unsigned short* __restrict__ Qb, const unsigned short* __restrict__ Kb,
    const unsigned short* __restrict__ VT, float* __restrict__ Oacc,
    float* __restrict__ Lacc) {
  __shared__ __align__(16) unsigned short KS[64 * 128];
  __shared__ __align__(16) unsigned short VS[128 * 72];
  const int id = blockIdx.x;
  const int xcd = id & 7;
  const int b = xcd >> 1;
  const int sub = 143 - ((id >> 3) * 2 + (xcd & 1));  // heavy-first
  int g = 0;
#pragma unroll
  for (int gg = 0; gg < 8; ++gg)
    if (sub >= 2 * (gg + 1) * (gg + 2)) g = gg + 1;
  const int off = sub - 2 * g * (g + 1);
  const int qt = 4 * g + off / (g + 1);
  const int s = off % (g + 1);
  const int q0 = qt * 128;
  const int klo = s * 512;
  const int khi = min((s + 1) * 512, (qt + 1) * 128);

  const int t = threadIdx.x;
  const int wv = t >> 6, lane = t & 63, quad = lane >> 4, l16 = lane & 15;
  const int qrow0 = q0 + wv * 32;
  const float SCL2 = 0.03125f * 1.44269504088896340736f;  // (1/32)*log2(e)

  const unsigned short* Kbb = Kb + (size_t)b * S_ * D_;
  const unsigned short* Vbb = VT + (size_t)b * D_ * S_;

  s8v Qf[2][4];
#pragma unroll
  for (int t2 = 0; t2 < 2; ++t2)
#pragma unroll
    for (int ks = 0; ks < 4; ++ks)
      Qf[t2][ks] = *reinterpret_cast<const s8v*>(
          Qb + ((size_t)b * S_ + qrow0 + t2 * 16 + l16) * D_ + ks * 32 + quad * 8);

  f4v O[2][8];
  const f4v fz = {0.f, 0.f, 0.f, 0.f};
#pragma unroll
  for (int t2 = 0; t2 < 2; ++t2)
#pragma unroll
    for (int nt = 0; nt < 8; ++nt) O[t2][nt] = fz;
  float lt[2] = {0.f, 0.f};

  // staging: K rows krow+16i (granule kgb); V d-rows vrow (granules vgb+i)
  const int krow = t >> 4, kgb = t & 15;
  const int vrow = t >> 1, vgb = (t & 1) * 4;

  s8v kr[4], vr[4];
#pragma unroll
  for (int i = 0; i < 4; ++i) {
    kr[i] = *reinterpret_cast<const s8v*>(
        Kbb + (size_t)(klo + krow + 16 * i) * D_ + kgb * 8);
    vr[i] = *reinterpret_cast<const s8v*>(
        Vbb + (size_t)vrow * S_ + klo + (vgb + i) * 8);
  }

  for (int k0 = klo; k0 < khi; k0 += 64) {
    __syncthreads();
#pragma unroll
    for (int i = 0; i < 4; ++i) {
      const int r = krow + 16 * i;
      const int sig = (krow & 3) | ((((krow >> 3) + 2 * i) & 3) << 2);
      *reinterpret_cast<s8v*>(KS + r * 128 + ((kgb ^ sig) * 8)) = kr[i];
      *reinterpret_cast<s8v*>(VS + vrow * 72 + (vgb + i) * 8) = vr[i];
    }
    __syncthreads();
    if (k0 + 64 < khi) {  // issue next-tile loads; in flight during compute
#pragma unroll
      for (int i = 0; i < 4; ++i) {
        kr[i] = *reinterpret_cast<const s8v*>(
            Kbb + (size_t)(k0 + 64 + krow + 16 * i) * D_ + kgb * 8);
        vr[i] = *reinterpret_cast<const s8v*>(
            Vbb + (size_t)vrow * S_ + k0 + 64 + (vgb + i) * 8);
      }
    }

    if (k0 <= qrow0 + 31) {  // wave-uniform causal skip
      f4v St[2][2][2];  // [chunk c][s2][t2]
#pragma unroll
      for (int c = 0; c < 2; ++c)
#pragma unroll
        for (int s2 = 0; s2 < 2; ++s2)
#pragma unroll
          for (int t2 = 0; t2 < 2; ++t2) St[c][s2][t2] = fz;
#pragma unroll
      for (int ks = 0; ks < 4; ++ks)
#pragma unroll
        for (int c = 0; c < 2; ++c)
#pragma unroll
          for (int s2 = 0; s2 < 2; ++s2) {
            const int row = c * 32 + ((l16 >> 2) << 3) + s2 * 4 + (l16 & 3);
            s8v kf = *reinterpret_cast<const s8v*>(
                KS + row * 128 + (((ks * 4 + quad) ^ l16) * 8));
#pragma unroll
            for (int t2 = 0; t2 < 2; ++t2)
              St[c][s2][t2] = __builtin_amdgcn_mfma_f32_16x16x32_bf16(
                  kf, Qf[t2][ks], St[c][s2][t2], 0, 0, 0);
          }
      const bool full = (k0 + 63 <= qrow0);
      s8v pf[2][2];  // [c][t2]
#pragma unroll
      for (int c = 0; c < 2; ++c)
#pragma unroll
        for (int t2 = 0; t2 < 2; ++t2) {
          float ladd = 0.f;
#pragma unroll
          for (int s2 = 0; s2 < 2; ++s2)
#pragma unroll
            for (int r = 0; r < 4; ++r) {
              float e = exp2f(St[c][s2][t2][r] * SCL2);
              if (!full) {
                int key = k0 + c * 32 + quad * 8 + s2 * 4 + r;
                if (key > qrow0 + t2 * 16 + l16) e = 0.f;
              }
              ladd += e;
              pf[c][t2][s2 * 4 + r] = (short)f2bf(e);
            }
          lt[t2] += ladd;
        }
#pragma unroll
      for (int c = 0; c < 2; ++c)
#pragma unroll
        for (int nt = 0; nt < 8; ++nt) {
          s8v vf = *reinterpret_cast<const s8v*>(
              VS + (nt * 16 + l16) * 72 + (c * 4 + quad) * 8);
#pragma unroll
          for (int t2 = 0; t2 < 2; ++t2)
            O[t2][nt] = __builtin_amdgcn_mfma_f32_16x16x32_bf16(
                pf[c][t2], vf, O[t2][nt], 0, 0, 0);
        }
    }
  }

  // epilogue: atomically accumulate partial (O, l)
#pragma unroll
  for (int t2 = 0; t2 < 2; ++t2) {
    lt[t2] += __shfl_xor(lt[t2], 16);
    lt[t2] += __shfl_xor(lt[t2], 32);
  }
  float* Ob = Oacc + (size_t)b * S_ * D_;
#pragma unroll
  for (int t2 = 0; t2 < 2; ++t2)
#pragma unroll
    for (int nt = 0; nt < 8; ++nt)
#pragma unroll
      for (int r = 0; r < 4; ++r)
        atomicAdd(&Ob[(size_t)(qrow0 + t2 * 16 + quad * 4 + r) * D_ +
                      nt * 16 + l16], O[t2][nt][r]);
  if (lane < 16) atomicAdd(&Lacc[(size_t)b * S_ + qrow0 + l16], lt[0]);
  else if (lane < 32) atomicAdd(&Lacc[(size_t)b * S_ + qrow0 + 16 + (lane & 15)], lt[1]);
}

// ---- normalize: out = Oacc / Lacc ------------------------------------------
__global__ __launch_bounds__(256) void norm_kernel(
    const float* __restrict__ Oacc, const float* __restrict__ Lacc,
    float* __restrict__ out) {
  const int idx = blockIdx.x * 256 + threadIdx.x;
  const int base = idx * 4;
  const int row = base >> 7;
  float4 o = reinterpret_cast<const float4*>(Oacc)[idx];
  float L = Lacc[row];
  float4 r;
  r.x = o.x / L; r.y = o.y / L; r.z = o.z / L; r.w = o.w / L;
  reinterpret_cast<float4*>(out)[idx] = r;
}

extern "C" void kernel_launch(void* const* d_in, const int* in_sizes, int n_in,
                              void* d_out, int out_size, void* d_ws, size_t ws_size,
                              hipStream_t stream) {
  const float* x = (const float*)d_in[0];
  const float* Wq = (const float*)d_in[1];
  const float* Wk = (const float*)d_in[2];
  const float* Wv = (const float*)d_in[3];
  float* out = (float*)d_out;

  char* ws = (char*)d_ws;
  unsigned short* Qb = (unsigned short*)ws;                           // 4 MB
  unsigned short* Kb = (unsigned short*)(ws + (((size_t)4) << 20));   // 4 MB
  unsigned short* VT = (unsigned short*)(ws + (((size_t)8) << 20));   // 4 MB
  unsigned short* Wt = (unsigned short*)(ws + (((size_t)12) << 20));  // 0.75 MB
  float* Oacc = (float*)(ws + (((size_t)13) << 20));                  // 8 MB
  float* Lacc = (float*)(ws + (((size_t)21) << 20));                  // 64 KB

  zero_kernel<<<2064, 256, 0, stream>>>(Oacc);  // covers Oacc+Lacc contiguous
  wcvt_kernel<<<dim3(32, 3), 256, 0, stream>>>(Wq, Wk, Wv, Wt);
  proj_kernel<<<768, 256, 0, stream>>>(x, Wt, Qb, Kb, VT);
  flash_kernel<<<576, 256, 0, stream>>>(Qb, Kb, VT, Oacc, Lacc);
  norm_kernel<<<2048, 256, 0, stream>>>(Oacc, Lacc, out);
}